// Round 8
// baseline (311.111 us; speedup 1.0000x reference)
//
#include <hip/hip_runtime.h>

#define BB 16
#define TT 2048
#define NROW 513
#define HOP 256
#define OUTLB 524288          // out length per batch
#define FTO 28                // output frames per block
#define SPAN (FTO*HOP)        // 7168
#define TILES 74              // ceil(2048/28)
#define NWG (BB*TILES)        // 1184 = 8*148 -> exact chunked XCD swizzle
#define CPX (NWG/8)           // 148 consecutive logical blocks per XCD

__device__ __forceinline__ int brev9(int k){ return (int)(__brev((unsigned)k)>>23); }
// bank swizzle: fold m[5:3]^m[8:6] into m[2:0], rotate by (2*row mod 16).
// Measured: conflicts 4.6e6 vs 1.14e7 unswizzled (r6 vs r0), correct output.
__device__ __forceinline__ int zidx(int r,int m){
  int s = m ^ ((m>>3)&7) ^ ((m>>6)&7);
  return (r<<9) + (s ^ ((2*r)&15));
}

// (512,4): VGPR budget = floor(256/min_waves) = 64 (measured r1/r2).
// Register plan (the r0..r7 lesson): persistent acc[7] (14 regs) + 32-float
// staging in flight cannot coexist under 64. The gather splits cleanly by
// half (Sb0 = a+4i+3|4): i<=2 complete after half 0, i>=4 only half 1,
// i==3 spans both -> gather per half into short-lived locals, write out
// immediately, carry ONE float2. Staging is fully unrolled again (r6's MLP).
__global__ __launch_bounds__(512,4) void istft_fused(
    const float* __restrict__ sr, const float* __restrict__ si,
    const float* __restrict__ win, float* __restrict__ out)
{
  __shared__ float2 zc[16*512];                    // 65536 B: frames T0..T0+15

  const int tid = threadIdx.x;
  // chunked XCD swizzle: each XCD owns 148 CONSECUTIVE (b,tile) ids so
  // straddled cache lines / 4-frame tile overlap are same-XCD L2 hits.
  const int d    = blockIdx.x;
  const int L    = (d & 7)*CPX + (d >> 3);
  const int b    = L / TILES;
  const int tile = L % TILES;
  const int Tbase= tile*FTO - 2;

  const int f  = tid & 7;                          // t-pair slot / frame slot
  const int pp = tid >> 3;                         // [0,64)
  const float* srb = sr + (size_t)b*NROW*TT;
  const float* sib = si + (size_t)b*NROW*TT;

  // Gather touches only m0 = r_w + 128*j, j=0..3. Keep j=0,1 in regs;
  // j=2,3 via Hann complement w[n+512] = 1 - w[n].
  const int r_w = (tid + 64) & 127;
  float2 wreg[2];
  #pragma unroll
  for (int j=0;j<2;++j) wreg[j] = ((const float2*)win)[r_w + 128*j];

  const bool edge = (tile==0)|(tile==TILES-1);
  float* outb = out + (size_t)b*OUTLB;
  const int gbase = tile*SPAN;

  // env division (1.5 interior; explicit Hann sum at the two edge tiles)
  auto writeOut = [&](int i, float2 r){
    const int p0 = 2*(tid + 512*i);
    const int gs = gbase + p0;
    if (gs < OUTLB){
      if (!edge){
        r.x *= (2.f/3.f); r.y *= (2.f/3.f);
      } else {
        #pragma unroll
        for (int e=0;e<2;++e){
          int l = gbase + 384 + p0 + e;
          int j0 = l & 255, tb = l >> 8;
          float env=0.f;
          #pragma unroll
          for (int mm=0;mm<4;++mm){
            int t2 = tb-mm;
            if (t2>=0 && t2<TT){
              float wv = 0.5f-0.5f*__cosf((float)(j0+256*mm)*0.006135923151542565f);
              env += wv*wv;
            }
          }
          ((float*)&r)[e] /= env;
        }
      }
      *(float2*)(outb+gs) = r;
    }
  };

  // build Z[row] entries for one frame (row in [0,16)) from spectrum row k
  auto storeZ = [&](int row, int k, float ar,float ai,float br,float bi,
                    float cr,float ci, float s_, float c_){
    if (k==0){
      zc[zidx(row,0)] = make_float2(0.5f*(ar+br), 0.5f*(ar-br));
      zc[zidx(row,1)] = make_float2(cr, -ci);      // brev9(256)=1, Z=conj(X[256])
    } else {
      float Er=0.5f*(ar+br), Ei=0.5f*(ai-bi);
      float Dr=0.5f*(ar-br), Di=0.5f*(ai+bi);
      float Or=Dr*c_-Di*s_, Oi=Dr*s_+Di*c_;
      zc[zidx(row,brev9(k))]     = make_float2(Er-Oi, Ei+Or);
      zc[zidx(row,brev9(512-k))] = make_float2(Er+Oi, Or-Ei);
    }
  };

  float2 carry = make_float2(0.f,0.f);             // acc[3] across halves

  #pragma unroll 1
  for (int half=0; half<2; ++half){
    const int T0 = Tbase + 16*half;
    const int ta = T0 + 2*f;                       // even
    const int tp = min(max(ta,0),TT-2);            // clamped, even -> 8B aligned
    const float m0_ = (ta>=0   && ta  <TT)?(1.f/512.f):0.f;
    const float m1_ = (ta+1>=0 && ta+1<TT)?(1.f/512.f):0.f;
    const float* srt = srb + tp;
    const float* sit = sib + tp;

    __syncthreads();                               // zc WAR vs previous gather

    // X[256] (k==0 storeZ path, pp==0 threads only)
    float2 vRc=make_float2(0.f,0.f), vIc=make_float2(0.f,0.f);
    if (pp==0){
      vRc = *(const float2*)(srt + (size_t)256*TT);
      vIc = *(const float2*)(sit + (size_t)256*TT);
    }

    // fully-unrolled staging: all 16 float2 loads issued back-to-back
    // (MLP); 8 lanes x 8B = full 64B row segment consumed per row.
    #pragma unroll
    for (int cc=0;cc<4;++cc){
      const int k = cc*64+pp;                      // [0,256)
      const float2 vRk = *(const float2*)(srt + (size_t)k*TT);
      const float2 vIk = *(const float2*)(sit + (size_t)k*TT);
      const float2 vRq = *(const float2*)(srt + (size_t)(512-k)*TT);
      const float2 vIq = *(const float2*)(sit + (size_t)(512-k)*TT);
      float s_,c_; __sincosf((float)k*0.006135923151542565f,&s_,&c_);  // e^{i*pi*k/512}
      storeZ(2*f,   k, vRk.x*m0_, vIk.x*m0_, vRq.x*m0_, vIq.x*m0_, vRc.x*m0_, vIc.x*m0_, s_, c_);
      storeZ(2*f+1, k, vRk.y*m1_, vIk.y*m1_, vRq.y*m1_, vIq.y*m1_, vRc.y*m1_, vIc.y*m1_, s_, c_);
    }

    // 512-pt FFT on both 8-row chunks between the same barriers
    // (4 radix-4 stages + radix-2; twiddles on the fly, shared across chunks)
    #pragma unroll
    for (int st=0; st<4; ++st){
      __syncthreads();
      const int h = 1<<(2*st);
      #pragma unroll
      for (int i=0;i<2;++i){
        const int q   = pp + 64*i;                 // [0,128)
        const int ilo = q & (h-1);
        const int base= ((q>>(2*st))<<(2*st+2)) + ilo;
        float2 w1, w2;
        if (st==0){ w1=make_float2(1.f,0.f); w2=w1; }
        else {
          float s1,c1,s2,c2;
          __sincosf((float)(ilo<<(8-2*st))*0.012271846303085130f,&s1,&c1);
          __sincosf((float)(ilo<<(7-2*st))*0.012271846303085130f,&s2,&c2);
          w1=make_float2(c1,s1); w2=make_float2(c2,s2);
        }
        #pragma unroll
        for (int ch=0; ch<2; ++ch){
          const int r = ch*8 + f;
          float2 e0=zc[zidx(r,base)],     e1=zc[zidx(r,base+h)];
          float2 e2=zc[zidx(r,base+2*h)], e3=zc[zidx(r,base+3*h)];
          float t1r=e1.x*w1.x-e1.y*w1.y, t1i=e1.x*w1.y+e1.y*w1.x;
          float t3r=e3.x*w1.x-e3.y*w1.y, t3i=e3.x*w1.y+e3.y*w1.x;
          float arr=e0.x+t1r, ari=e0.y+t1i, brr=e0.x-t1r, bri=e0.y-t1i;
          float crr=e2.x+t3r, cri=e2.y+t3i, drr=e2.x-t3r, dri=e2.y-t3i;
          float cwr=crr*w2.x-cri*w2.y, cwi=crr*w2.y+cri*w2.x;
          float dwr=drr*w2.x-dri*w2.y, dwi=drr*w2.y+dri*w2.x;
          zc[zidx(r,base)]     = make_float2(arr+cwr, ari+cwi);
          zc[zidx(r,base+2*h)] = make_float2(arr-cwr, ari-cwi);
          zc[zidx(r,base+h)]   = make_float2(brr-dwi, bri+dwr);  // W^128=+i
          zc[zidx(r,base+3*h)] = make_float2(brr+dwi, bri-dwr);
        }
      }
    }
    __syncthreads();
    #pragma unroll
    for (int i=0;i<4;++i){                         // final radix-2, h=256
      const int q = pp + 64*i;                     // [0,256)
      float sq,cq; __sincosf((float)q*0.012271846303085130f,&sq,&cq);
      #pragma unroll
      for (int ch=0; ch<2; ++ch){
        const int r = ch*8 + f;
        float2 u = zc[zidx(r,q)], v = zc[zidx(r,q+256)];
        float tr=v.x*cq-v.y*sq, ti=v.x*sq+v.y*cq;
        zc[zidx(r,q)]     = make_float2(u.x+tr, u.y+ti);
        zc[zidx(r,q+256)] = make_float2(u.x-tr, u.y-ti);
      }
    }

    // per-half gather + immediate writeout. m0 = r_w + 128*j, S = Sb - j,
    // Sb = (base - r_w)>>7 exact; half 0 covers output slots i=0..3,
    // half 1 covers i=3..6 (i==3 carried between).
    __syncthreads();
    if (half==0){
      float2 a4[4];
      #pragma unroll
      for (int ii=0;ii<4;++ii) a4[ii]=make_float2(0.f,0.f);
      #pragma unroll
      for (int ii=0;ii<4;++ii){
        const int base = tid + 512*ii + 448;       // boff(half=0)=448
        const int Sb   = (base - r_w) >> 7;
        #pragma unroll
        for (int j=0;j<4;++j){
          const int S = Sb - j;
          if (S >= 0 && S < 16){
            float2 v = zc[zidx(S, r_w + 128*j)];
            const float wx = (j<2)? wreg[j].x : 1.f - wreg[j-2].x;
            const float wy = (j<2)? wreg[j].y : 1.f - wreg[j-2].y;
            a4[ii].x += v.x*wx;
            a4[ii].y += v.y*wy;
          }
        }
      }
      writeOut(0,a4[0]); writeOut(1,a4[1]); writeOut(2,a4[2]);
      carry = a4[3];
    } else {
      float2 a4[4];
      a4[0]=carry;
      #pragma unroll
      for (int ii=1;ii<4;++ii) a4[ii]=make_float2(0.f,0.f);
      #pragma unroll
      for (int ii=0;ii<4;++ii){                    // i = ii+3
        const int base = tid + 512*ii - 64;        // tid+512*(ii+3)+448-2048
        const int Sb   = (base - r_w) >> 7;
        #pragma unroll
        for (int j=0;j<4;++j){
          const int S = Sb - j;
          if (S >= 0 && S < 16){
            float2 v = zc[zidx(S, r_w + 128*j)];
            const float wx = (j<2)? wreg[j].x : 1.f - wreg[j-2].x;
            const float wy = (j<2)? wreg[j].y : 1.f - wreg[j-2].y;
            a4[ii].x += v.x*wx;
            a4[ii].y += v.y*wy;
          }
        }
      }
      writeOut(3,a4[0]); writeOut(4,a4[1]); writeOut(5,a4[2]); writeOut(6,a4[3]);
    }
  }
}

extern "C" void kernel_launch(void* const* d_in, const int* in_sizes, int n_in,
                              void* d_out, int out_size, void* d_ws, size_t ws_size,
                              hipStream_t stream) {
  const float* sr = (const float*)d_in[0];
  const float* si = (const float*)d_in[1];
  const float* w  = (const float*)d_in[2];
  float* out = (float*)d_out;
  istft_fused<<<NWG, 512, 0, stream>>>(sr, si, w, out);
}

// Round 9
// 240.826 us; speedup vs baseline: 1.2919x; 1.2919x over previous
//
#include <hip/hip_runtime.h>

#define BB 16
#define TT 2048
#define NROW 513
#define HOP 256
#define OUTLB 524288          // out length per batch
#define FTO 28                // output frames per block
#define SPAN (FTO*HOP)        // 7168
#define TILES 74              // ceil(2048/28)
#define NWG (BB*TILES)        // 1184 = 8*148 -> exact chunked XCD swizzle
#define CPX (NWG/8)           // 148 consecutive logical blocks per XCD

__device__ __forceinline__ int brev9(int k){ return (int)(__brev((unsigned)k)>>23); }
// bank swizzle: fold m[5:3]^m[8:6] into m[2:0], rotate by (2*row mod 16).
// Measured: conflicts 4.6e6 vs 1.14e7 unswizzled (r6 vs r0), correct output.
__device__ __forceinline__ int zidx(int r,int m){
  int s = m ^ ((m>>3)&7) ^ ((m>>6)&7);
  return (r<<9) + (s ^ ((2*r)&15));
}

// launch_bounds(512,2): VGPR budget = floor(256/min_waves) = 128 (measured
// family: (512,8)->32, (512,6)->40, (512,4)->64). This kernel's true peak
// live set is ~90-100 regs (32 staging floats in flight + storeZ temps +
// gather locals); under the old 64-reg budget every structural variant
// (r3..r8) spilled 100-220MB of scratch. Occupancy is UNCHANGED by the
// raise: 64KB LDS already caps residency at 2 blocks/CU, and 65..128-VGPR
// kernels still get 4 waves/SIMD = 16 waves/CU = 2x512thr (m69 steps).
__global__ __launch_bounds__(512,2) void istft_fused(
    const float* __restrict__ sr, const float* __restrict__ si,
    const float* __restrict__ win, float* __restrict__ out)
{
  __shared__ float2 zc[16*512];                    // 65536 B: frames T0..T0+15

  const int tid = threadIdx.x;
  // chunked XCD swizzle: each XCD owns 148 CONSECUTIVE (b,tile) ids so
  // straddled cache lines / 4-frame tile overlap are same-XCD L2 hits.
  const int d    = blockIdx.x;
  const int L    = (d & 7)*CPX + (d >> 3);
  const int b    = L / TILES;
  const int tile = L % TILES;
  const int Tbase= tile*FTO - 2;

  const int f  = tid & 7;                          // t-pair slot / frame slot
  const int pp = tid >> 3;                         // [0,64)
  const float* srb = sr + (size_t)b*NROW*TT;
  const float* sib = si + (size_t)b*NROW*TT;

  // Gather touches only m0 = r_w + 128*j, j=0..3. Keep j=0,1 in regs;
  // j=2,3 via Hann complement w[n+512] = 1 - w[n].
  const int r_w = (tid + 64) & 127;
  float2 wreg[2];
  #pragma unroll
  for (int j=0;j<2;++j) wreg[j] = ((const float2*)win)[r_w + 128*j];

  const bool edge = (tile==0)|(tile==TILES-1);
  float* outb = out + (size_t)b*OUTLB;
  const int gbase = tile*SPAN;

  // env division (1.5 interior; explicit Hann sum at the two edge tiles)
  auto writeOut = [&](int i, float2 r){
    const int p0 = 2*(tid + 512*i);
    const int gs = gbase + p0;
    if (gs < OUTLB){
      if (!edge){
        r.x *= (2.f/3.f); r.y *= (2.f/3.f);
      } else {
        #pragma unroll
        for (int e=0;e<2;++e){
          int l = gbase + 384 + p0 + e;
          int j0 = l & 255, tb = l >> 8;
          float env=0.f;
          #pragma unroll
          for (int mm=0;mm<4;++mm){
            int t2 = tb-mm;
            if (t2>=0 && t2<TT){
              float wv = 0.5f-0.5f*__cosf((float)(j0+256*mm)*0.006135923151542565f);
              env += wv*wv;
            }
          }
          ((float*)&r)[e] /= env;
        }
      }
      *(float2*)(outb+gs) = r;
    }
  };

  // build Z[row] entries for one frame (row in [0,16)) from spectrum row k
  auto storeZ = [&](int row, int k, float ar,float ai,float br,float bi,
                    float cr,float ci, float s_, float c_){
    if (k==0){
      zc[zidx(row,0)] = make_float2(0.5f*(ar+br), 0.5f*(ar-br));
      zc[zidx(row,1)] = make_float2(cr, -ci);      // brev9(256)=1, Z=conj(X[256])
    } else {
      float Er=0.5f*(ar+br), Ei=0.5f*(ai-bi);
      float Dr=0.5f*(ar-br), Di=0.5f*(ai+bi);
      float Or=Dr*c_-Di*s_, Oi=Dr*s_+Di*c_;
      zc[zidx(row,brev9(k))]     = make_float2(Er-Oi, Ei+Or);
      zc[zidx(row,brev9(512-k))] = make_float2(Er+Oi, Or-Ei);
    }
  };

  float2 carry = make_float2(0.f,0.f);             // acc[3] across halves

  #pragma unroll 1
  for (int half=0; half<2; ++half){
    const int T0 = Tbase + 16*half;
    const int ta = T0 + 2*f;                       // even
    const int tp = min(max(ta,0),TT-2);            // clamped, even -> 8B aligned
    const float m0_ = (ta>=0   && ta  <TT)?(1.f/512.f):0.f;
    const float m1_ = (ta+1>=0 && ta+1<TT)?(1.f/512.f):0.f;
    const float* srt = srb + tp;
    const float* sit = sib + tp;

    __syncthreads();                               // zc WAR vs previous gather

    // X[256] (k==0 storeZ path, pp==0 threads only)
    float2 vRc=make_float2(0.f,0.f), vIc=make_float2(0.f,0.f);
    if (pp==0){
      vRc = *(const float2*)(srt + (size_t)256*TT);
      vIc = *(const float2*)(sit + (size_t)256*TT);
    }

    // fully-unrolled staging: all 16 float2 loads issued back-to-back
    // (MLP); 8 lanes x 8B = full 64B row segment consumed per row.
    #pragma unroll
    for (int cc=0;cc<4;++cc){
      const int k = cc*64+pp;                      // [0,256)
      const float2 vRk = *(const float2*)(srt + (size_t)k*TT);
      const float2 vIk = *(const float2*)(sit + (size_t)k*TT);
      const float2 vRq = *(const float2*)(srt + (size_t)(512-k)*TT);
      const float2 vIq = *(const float2*)(sit + (size_t)(512-k)*TT);
      float s_,c_; __sincosf((float)k*0.006135923151542565f,&s_,&c_);  // e^{i*pi*k/512}
      storeZ(2*f,   k, vRk.x*m0_, vIk.x*m0_, vRq.x*m0_, vIq.x*m0_, vRc.x*m0_, vIc.x*m0_, s_, c_);
      storeZ(2*f+1, k, vRk.y*m1_, vIk.y*m1_, vRq.y*m1_, vIq.y*m1_, vRc.y*m1_, vIc.y*m1_, s_, c_);
    }

    // 512-pt FFT on both 8-row chunks between the same barriers
    // (4 radix-4 stages + radix-2; twiddles on the fly, shared across chunks)
    #pragma unroll
    for (int st=0; st<4; ++st){
      __syncthreads();
      const int h = 1<<(2*st);
      #pragma unroll
      for (int i=0;i<2;++i){
        const int q   = pp + 64*i;                 // [0,128)
        const int ilo = q & (h-1);
        const int base= ((q>>(2*st))<<(2*st+2)) + ilo;
        float2 w1, w2;
        if (st==0){ w1=make_float2(1.f,0.f); w2=w1; }
        else {
          float s1,c1,s2,c2;
          __sincosf((float)(ilo<<(8-2*st))*0.012271846303085130f,&s1,&c1);
          __sincosf((float)(ilo<<(7-2*st))*0.012271846303085130f,&s2,&c2);
          w1=make_float2(c1,s1); w2=make_float2(c2,s2);
        }
        #pragma unroll
        for (int ch=0; ch<2; ++ch){
          const int r = ch*8 + f;
          float2 e0=zc[zidx(r,base)],     e1=zc[zidx(r,base+h)];
          float2 e2=zc[zidx(r,base+2*h)], e3=zc[zidx(r,base+3*h)];
          float t1r=e1.x*w1.x-e1.y*w1.y, t1i=e1.x*w1.y+e1.y*w1.x;
          float t3r=e3.x*w1.x-e3.y*w1.y, t3i=e3.x*w1.y+e3.y*w1.x;
          float arr=e0.x+t1r, ari=e0.y+t1i, brr=e0.x-t1r, bri=e0.y-t1i;
          float crr=e2.x+t3r, cri=e2.y+t3i, drr=e2.x-t3r, dri=e2.y-t3i;
          float cwr=crr*w2.x-cri*w2.y, cwi=crr*w2.y+cri*w2.x;
          float dwr=drr*w2.x-dri*w2.y, dwi=drr*w2.y+dri*w2.x;
          zc[zidx(r,base)]     = make_float2(arr+cwr, ari+cwi);
          zc[zidx(r,base+2*h)] = make_float2(arr-cwr, ari-cwi);
          zc[zidx(r,base+h)]   = make_float2(brr-dwi, bri+dwr);  // W^128=+i
          zc[zidx(r,base+3*h)] = make_float2(brr+dwi, bri-dwr);
        }
      }
    }
    __syncthreads();
    #pragma unroll
    for (int i=0;i<4;++i){                         // final radix-2, h=256
      const int q = pp + 64*i;                     // [0,256)
      float sq,cq; __sincosf((float)q*0.012271846303085130f,&sq,&cq);
      #pragma unroll
      for (int ch=0; ch<2; ++ch){
        const int r = ch*8 + f;
        float2 u = zc[zidx(r,q)], v = zc[zidx(r,q+256)];
        float tr=v.x*cq-v.y*sq, ti=v.x*sq+v.y*cq;
        zc[zidx(r,q)]     = make_float2(u.x+tr, u.y+ti);
        zc[zidx(r,q+256)] = make_float2(u.x-tr, u.y-ti);
      }
    }

    // per-half gather + immediate writeout. m0 = r_w + 128*j, S = Sb - j,
    // Sb = (base - r_w)>>7 exact; half 0 covers output slots i=0..3,
    // half 1 covers i=3..6 (i==3 carried between).
    __syncthreads();
    if (half==0){
      float2 a4[4];
      #pragma unroll
      for (int ii=0;ii<4;++ii) a4[ii]=make_float2(0.f,0.f);
      #pragma unroll
      for (int ii=0;ii<4;++ii){
        const int base = tid + 512*ii + 448;       // boff(half=0)=448
        const int Sb   = (base - r_w) >> 7;
        #pragma unroll
        for (int j=0;j<4;++j){
          const int S = Sb - j;
          if (S >= 0 && S < 16){
            float2 v = zc[zidx(S, r_w + 128*j)];
            const float wx = (j<2)? wreg[j].x : 1.f - wreg[j-2].x;
            const float wy = (j<2)? wreg[j].y : 1.f - wreg[j-2].y;
            a4[ii].x += v.x*wx;
            a4[ii].y += v.y*wy;
          }
        }
      }
      writeOut(0,a4[0]); writeOut(1,a4[1]); writeOut(2,a4[2]);
      carry = a4[3];
    } else {
      float2 a4[4];
      a4[0]=carry;
      #pragma unroll
      for (int ii=1;ii<4;++ii) a4[ii]=make_float2(0.f,0.f);
      #pragma unroll
      for (int ii=0;ii<4;++ii){                    // i = ii+3
        const int base = tid + 512*ii - 64;        // tid+512*(ii+3)+448-2048
        const int Sb   = (base - r_w) >> 7;
        #pragma unroll
        for (int j=0;j<4;++j){
          const int S = Sb - j;
          if (S >= 0 && S < 16){
            float2 v = zc[zidx(S, r_w + 128*j)];
            const float wx = (j<2)? wreg[j].x : 1.f - wreg[j-2].x;
            const float wy = (j<2)? wreg[j].y : 1.f - wreg[j-2].y;
            a4[ii].x += v.x*wx;
            a4[ii].y += v.y*wy;
          }
        }
      }
      writeOut(3,a4[0]); writeOut(4,a4[1]); writeOut(5,a4[2]); writeOut(6,a4[3]);
    }
  }
}

extern "C" void kernel_launch(void* const* d_in, const int* in_sizes, int n_in,
                              void* d_out, int out_size, void* d_ws, size_t ws_size,
                              hipStream_t stream) {
  const float* sr = (const float*)d_in[0];
  const float* si = (const float*)d_in[1];
  const float* w  = (const float*)d_in[2];
  float* out = (float*)d_out;
  istft_fused<<<NWG, 512, 0, stream>>>(sr, si, w, out);
}

// Round 11
// 240.487 us; speedup vs baseline: 1.2937x; 1.0014x over previous
//
#include <hip/hip_runtime.h>

#define BB 16
#define TT 2048
#define NROW 513
#define HOP 256
#define OUTLB 524288          // out length per batch
#define FTO 28                // output frames per block
#define SPAN (FTO*HOP)        // 7168
#define TILES 74              // ceil(2048/28)
#define NWG (BB*TILES)        // 1184 = 8*148 -> exact chunked XCD swizzle
#define CPX (NWG/8)           // 148 consecutive logical blocks per XCD

__device__ __forceinline__ int brev9(int k){ return (int)(__brev((unsigned)k)>>23); }
// bank swizzle: fold m[5:3]^m[8:6] into m[2:0], rotate by (2*row mod 16).
// Measured: conflicts 4.6e6 vs 1.14e7 unswizzled (r6 vs r0), correct output.
__device__ __forceinline__ int zidx(int r,int m){
  int s = m ^ ((m>>3)&7) ^ ((m>>6)&7);
  return (r<<9) + (s ^ ((2*r)&15));
}

// Launch-bounds decode (measured r0/r1/r2/r9): __launch_bounds__(512,N) sets
// waves-per-EU as BOTH min and max on this toolchain -> VGPR budget 256/N AND
// residency cap 4N waves/CU. (512,2) fixed the spills (VGPR 120, WRITE at the
// 33MB ideal) but capped residency at 1 block/CU (Occ 21%) -> latency-bound.
// r10's amdgpu_waves_per_eu(4) attribute broke the build (container fail x2,
// only delta vs passing r9). Mechanism that needs no exotic attribute:
// ONE-ARG __launch_bounds__(512). The backend derives the occupancy target
// from LDS (64KB -> 2 blocks/CU -> 4 waves/EU) and caps VGPRs at ~128 so
// registers don't bind below that -> no-spill allocation AND 2 blocks/CU.
__global__ __launch_bounds__(512) void istft_fused(
    const float* __restrict__ sr, const float* __restrict__ si,
    const float* __restrict__ win, float* __restrict__ out)
{
  __shared__ float2 zc[16*512];                    // 65536 B: frames T0..T0+15

  const int tid = threadIdx.x;
  // chunked XCD swizzle: each XCD owns 148 CONSECUTIVE (b,tile) ids so
  // straddled cache lines / 4-frame tile overlap are same-XCD L2 hits.
  const int d    = blockIdx.x;
  const int L    = (d & 7)*CPX + (d >> 3);
  const int b    = L / TILES;
  const int tile = L % TILES;
  const int Tbase= tile*FTO - 2;

  const int f  = tid & 7;                          // t-pair slot / frame slot
  const int pp = tid >> 3;                         // [0,64)
  const float* srb = sr + (size_t)b*NROW*TT;
  const float* sib = si + (size_t)b*NROW*TT;

  // Gather touches only m0 = r_w + 128*j, j=0..3. Keep j=0,1 in regs;
  // j=2,3 via Hann complement w[n+512] = 1 - w[n].
  const int r_w = (tid + 64) & 127;
  float2 wreg[2];
  #pragma unroll
  for (int j=0;j<2;++j) wreg[j] = ((const float2*)win)[r_w + 128*j];

  const bool edge = (tile==0)|(tile==TILES-1);
  float* outb = out + (size_t)b*OUTLB;
  const int gbase = tile*SPAN;

  // env division (1.5 interior; explicit Hann sum at the two edge tiles)
  auto writeOut = [&](int i, float2 r){
    const int p0 = 2*(tid + 512*i);
    const int gs = gbase + p0;
    if (gs < OUTLB){
      if (!edge){
        r.x *= (2.f/3.f); r.y *= (2.f/3.f);
      } else {
        #pragma unroll
        for (int e=0;e<2;++e){
          int l = gbase + 384 + p0 + e;
          int j0 = l & 255, tb = l >> 8;
          float env=0.f;
          #pragma unroll
          for (int mm=0;mm<4;++mm){
            int t2 = tb-mm;
            if (t2>=0 && t2<TT){
              float wv = 0.5f-0.5f*__cosf((float)(j0+256*mm)*0.006135923151542565f);
              env += wv*wv;
            }
          }
          ((float*)&r)[e] /= env;
        }
      }
      *(float2*)(outb+gs) = r;
    }
  };

  // build Z[row] entries for one frame (row in [0,16)) from spectrum row k
  auto storeZ = [&](int row, int k, float ar,float ai,float br,float bi,
                    float cr,float ci, float s_, float c_){
    if (k==0){
      zc[zidx(row,0)] = make_float2(0.5f*(ar+br), 0.5f*(ar-br));
      zc[zidx(row,1)] = make_float2(cr, -ci);      // brev9(256)=1, Z=conj(X[256])
    } else {
      float Er=0.5f*(ar+br), Ei=0.5f*(ai-bi);
      float Dr=0.5f*(ar-br), Di=0.5f*(ai+bi);
      float Or=Dr*c_-Di*s_, Oi=Dr*s_+Di*c_;
      zc[zidx(row,brev9(k))]     = make_float2(Er-Oi, Ei+Or);
      zc[zidx(row,brev9(512-k))] = make_float2(Er+Oi, Or-Ei);
    }
  };

  float2 carry = make_float2(0.f,0.f);             // acc[3] across halves

  #pragma unroll 1
  for (int half=0; half<2; ++half){
    const int T0 = Tbase + 16*half;
    const int ta = T0 + 2*f;                       // even
    const int tp = min(max(ta,0),TT-2);            // clamped, even -> 8B aligned
    const float m0_ = (ta>=0   && ta  <TT)?(1.f/512.f):0.f;
    const float m1_ = (ta+1>=0 && ta+1<TT)?(1.f/512.f):0.f;
    const float* srt = srb + tp;
    const float* sit = sib + tp;

    __syncthreads();                               // zc WAR vs previous gather

    // X[256] (k==0 storeZ path, pp==0 threads only)
    float2 vRc=make_float2(0.f,0.f), vIc=make_float2(0.f,0.f);
    if (pp==0){
      vRc = *(const float2*)(srt + (size_t)256*TT);
      vIc = *(const float2*)(sit + (size_t)256*TT);
    }

    // fully-unrolled staging: all 16 float2 loads issued back-to-back
    // (MLP); 8 lanes x 8B = full 64B row segment consumed per row.
    #pragma unroll
    for (int cc=0;cc<4;++cc){
      const int k = cc*64+pp;                      // [0,256)
      const float2 vRk = *(const float2*)(srt + (size_t)k*TT);
      const float2 vIk = *(const float2*)(sit + (size_t)k*TT);
      const float2 vRq = *(const float2*)(srt + (size_t)(512-k)*TT);
      const float2 vIq = *(const float2*)(sit + (size_t)(512-k)*TT);
      float s_,c_; __sincosf((float)k*0.006135923151542565f,&s_,&c_);  // e^{i*pi*k/512}
      storeZ(2*f,   k, vRk.x*m0_, vIk.x*m0_, vRq.x*m0_, vIq.x*m0_, vRc.x*m0_, vIc.x*m0_, s_, c_);
      storeZ(2*f+1, k, vRk.y*m1_, vIk.y*m1_, vRq.y*m1_, vIq.y*m1_, vRc.y*m1_, vIc.y*m1_, s_, c_);
    }

    // 512-pt FFT on both 8-row chunks between the same barriers
    // (4 radix-4 stages + radix-2; twiddles on the fly, shared across chunks)
    #pragma unroll
    for (int st=0; st<4; ++st){
      __syncthreads();
      const int h = 1<<(2*st);
      #pragma unroll
      for (int i=0;i<2;++i){
        const int q   = pp + 64*i;                 // [0,128)
        const int ilo = q & (h-1);
        const int base= ((q>>(2*st))<<(2*st+2)) + ilo;
        float2 w1, w2;
        if (st==0){ w1=make_float2(1.f,0.f); w2=w1; }
        else {
          float s1,c1,s2,c2;
          __sincosf((float)(ilo<<(8-2*st))*0.012271846303085130f,&s1,&c1);
          __sincosf((float)(ilo<<(7-2*st))*0.012271846303085130f,&s2,&c2);
          w1=make_float2(c1,s1); w2=make_float2(c2,s2);
        }
        #pragma unroll
        for (int ch=0; ch<2; ++ch){
          const int r = ch*8 + f;
          float2 e0=zc[zidx(r,base)],     e1=zc[zidx(r,base+h)];
          float2 e2=zc[zidx(r,base+2*h)], e3=zc[zidx(r,base+3*h)];
          float t1r=e1.x*w1.x-e1.y*w1.y, t1i=e1.x*w1.y+e1.y*w1.x;
          float t3r=e3.x*w1.x-e3.y*w1.y, t3i=e3.x*w1.y+e3.y*w1.x;
          float arr=e0.x+t1r, ari=e0.y+t1i, brr=e0.x-t1r, bri=e0.y-t1i;
          float crr=e2.x+t3r, cri=e2.y+t3i, drr=e2.x-t3r, dri=e2.y-t3i;
          float cwr=crr*w2.x-cri*w2.y, cwi=crr*w2.y+cri*w2.x;
          float dwr=drr*w2.x-dri*w2.y, dwi=drr*w2.y+dri*w2.x;
          zc[zidx(r,base)]     = make_float2(arr+cwr, ari+cwi);
          zc[zidx(r,base+2*h)] = make_float2(arr-cwr, ari-cwi);
          zc[zidx(r,base+h)]   = make_float2(brr-dwi, bri+dwr);  // W^128=+i
          zc[zidx(r,base+3*h)] = make_float2(brr+dwi, bri-dwr);
        }
      }
    }
    __syncthreads();
    #pragma unroll
    for (int i=0;i<4;++i){                         // final radix-2, h=256
      const int q = pp + 64*i;                     // [0,256)
      float sq,cq; __sincosf((float)q*0.012271846303085130f,&sq,&cq);
      #pragma unroll
      for (int ch=0; ch<2; ++ch){
        const int r = ch*8 + f;
        float2 u = zc[zidx(r,q)], v = zc[zidx(r,q+256)];
        float tr=v.x*cq-v.y*sq, ti=v.x*sq+v.y*cq;
        zc[zidx(r,q)]     = make_float2(u.x+tr, u.y+ti);
        zc[zidx(r,q+256)] = make_float2(u.x-tr, u.y-ti);
      }
    }

    // per-half gather + immediate writeout. m0 = r_w + 128*j, S = Sb - j,
    // Sb = (base - r_w)>>7 exact; half 0 covers output slots i=0..3,
    // half 1 covers i=3..6 (i==3 carried between).
    __syncthreads();
    if (half==0){
      float2 a4[4];
      #pragma unroll
      for (int ii=0;ii<4;++ii) a4[ii]=make_float2(0.f,0.f);
      #pragma unroll
      for (int ii=0;ii<4;++ii){
        const int base = tid + 512*ii + 448;       // boff(half=0)=448
        const int Sb   = (base - r_w) >> 7;
        #pragma unroll
        for (int j=0;j<4;++j){
          const int S = Sb - j;
          if (S >= 0 && S < 16){
            float2 v = zc[zidx(S, r_w + 128*j)];
            const float wx = (j<2)? wreg[j].x : 1.f - wreg[j-2].x;
            const float wy = (j<2)? wreg[j].y : 1.f - wreg[j-2].y;
            a4[ii].x += v.x*wx;
            a4[ii].y += v.y*wy;
          }
        }
      }
      writeOut(0,a4[0]); writeOut(1,a4[1]); writeOut(2,a4[2]);
      carry = a4[3];
    } else {
      float2 a4[4];
      a4[0]=carry;
      #pragma unroll
      for (int ii=1;ii<4;++ii) a4[ii]=make_float2(0.f,0.f);
      #pragma unroll
      for (int ii=0;ii<4;++ii){                    // i = ii+3
        const int base = tid + 512*ii - 64;        // tid+512*(ii+3)+448-2048
        const int Sb   = (base - r_w) >> 7;
        #pragma unroll
        for (int j=0;j<4;++j){
          const int S = Sb - j;
          if (S >= 0 && S < 16){
            float2 v = zc[zidx(S, r_w + 128*j)];
            const float wx = (j<2)? wreg[j].x : 1.f - wreg[j-2].x;
            const float wy = (j<2)? wreg[j].y : 1.f - wreg[j-2].y;
            a4[ii].x += v.x*wx;
            a4[ii].y += v.y*wy;
          }
        }
      }
      writeOut(3,a4[0]); writeOut(4,a4[1]); writeOut(5,a4[2]); writeOut(6,a4[3]);
    }
  }
}

extern "C" void kernel_launch(void* const* d_in, const int* in_sizes, int n_in,
                              void* d_out, int out_size, void* d_ws, size_t ws_size,
                              hipStream_t stream) {
  const float* sr = (const float*)d_in[0];
  const float* si = (const float*)d_in[1];
  const float* w  = (const float*)d_in[2];
  float* out = (float*)d_out;
  istft_fused<<<NWG, 512, 0, stream>>>(sr, si, w, out);
}